// Round 3
// baseline (2861.881 us; speedup 1.0000x reference)
//
#include <hip/hip_runtime.h>
#include <hip/hip_bf16.h>
#include <math.h>

// Problem constants
#define B 64
#define S 64
#define T 21
#define ENC_D 512
#define HID 512
#define EMB 512
#define STYLE 128
#define VOCAB 32000

typedef __bf16 bf16x8 __attribute__((ext_vector_type(8)));
typedef float f32x4 __attribute__((ext_vector_type(4)));

__device__ __forceinline__ unsigned short f32_to_bf16_rne(float x) {
    union { float f; unsigned int u; } v;
    v.f = x;
    unsigned int u = v.u;
    unsigned int r = (u + 0x7FFFu + ((u >> 16) & 1u)) >> 16;
    return (unsigned short)r;
}

__device__ __forceinline__ float bf16_to_f32(unsigned short x) {
    union { unsigned int u; float f; } v;
    v.u = ((unsigned int)x) << 16;
    return v.f;
}

// Grid-wide barrier: monotone counter, no reset. All blocks must call equally.
__device__ __forceinline__ void grid_sync_fn(unsigned* bar, unsigned target) {
    __threadfence();
    __syncthreads();
    if (threadIdx.x == 0) {
        __hip_atomic_fetch_add(bar, 1u, __ATOMIC_ACQ_REL, __HIP_MEMORY_SCOPE_AGENT);
        while (__hip_atomic_load(bar, __ATOMIC_ACQUIRE, __HIP_MEMORY_SCOPE_AGENT) < target) {
            __builtin_amdgcn_s_sleep(1);
        }
    }
    __syncthreads();
    __threadfence();
}

// ---------------------------------------------------------------------------
// Kernel A: h0 = concat(encode_hidden, style_emb[:,3,:]) @ W_e2d_w.T + b ; c0=0
// ---------------------------------------------------------------------------
__global__ void h0_kernel(const float* __restrict__ enc_h,
                          const float* __restrict__ style,
                          const float* __restrict__ W,
                          const float* __restrict__ bias,
                          float* __restrict__ h, float* __restrict__ c) {
    int b = blockIdx.x;
    int tid = threadIdx.x;
    __shared__ __attribute__((aligned(16))) float in[640];
    for (int i = tid; i < 512; i += 256) in[i] = enc_h[b * 512 + i];
    if (tid < 128) in[512 + tid] = style[b * 512 + 384 + tid];  // style[b][3][tid]
    __syncthreads();
    for (int j = tid; j < 512; j += 256) {
        const float4* w4 = (const float4*)(W + (size_t)j * 640);
        float acc = 0.f;
#pragma unroll 4
        for (int k4 = 0; k4 < 160; k4++) {
            float4 w = w4[k4];
            float4 iv = *(const float4*)(in + k4 * 4);
            acc += w.x * iv.x + w.y * iv.y + w.z * iv.z + w.w * iv.w;
        }
        h[b * 512 + j] = acc + bias[j];
        c[b * 512 + j] = 0.f;
    }
}

// ---------------------------------------------------------------------------
// proj_w fp32 -> bf16. grid(8000), block(256)
// ---------------------------------------------------------------------------
__global__ void wconv_kernel(const float* __restrict__ w,
                             unsigned short* __restrict__ wbf) {
    size_t i = ((size_t)blockIdx.x * 256 + threadIdx.x) * 8;
    float4 a = *(const float4*)(w + i);
    float4 b = *(const float4*)(w + i + 4);
    ushort4 lo, hi;
    lo.x = f32_to_bf16_rne(a.x); lo.y = f32_to_bf16_rne(a.y);
    lo.z = f32_to_bf16_rne(a.z); lo.w = f32_to_bf16_rne(a.w);
    hi.x = f32_to_bf16_rne(b.x); hi.y = f32_to_bf16_rne(b.y);
    hi.z = f32_to_bf16_rne(b.z); hi.w = f32_to_bf16_rne(b.w);
    *(ushort4*)(wbf + i) = lo;
    *(ushort4*)(wbf + i + 4) = hi;
}

// ---------------------------------------------------------------------------
// Precompute bf16 embeddings for all (b,t). grid(64*21), block(256)
// ---------------------------------------------------------------------------
__global__ void ebf_kernel(const float* __restrict__ emb_table,
                           const int* __restrict__ dec_in,
                           unsigned short* __restrict__ ebf) {
    int bt = blockIdx.x;           // b*T + t
    int tid = threadIdx.x;
    int token = dec_in[bt];
    const float* src = emb_table + (size_t)token * 512;
    unsigned short* dst = ebf + (size_t)bt * 512;
    dst[tid] = f32_to_bf16_rne(src[tid]);
    dst[tid + 256] = f32_to_bf16_rne(src[tid + 256]);
}

// ---------------------------------------------------------------------------
// Fused recurrent scan: 21 timesteps in one cooperative launch.
// grid(128), block(256). Block g owns gate rows n0=g*16..+16 (weights in LDS
// as bf16, padded stride 1544). Per step:
//   Phase A: blocks 0..63  : attention for batch row b=g (scores/softmax/ctx),
//            blocks 64..127: stage emb slice for this t into xbf.
//   Phase B: all blocks: gates[64][16-cols] via mfma_16x16x32_bf16.
//   Phase C: block g: LSTM pointwise for (b=g>>1, half=g&1) + partial h@attn_W.
// ---------------------------------------------------------------------------
__global__ void fused_scan_kernel(const float* __restrict__ enc_out,
                                  const float* __restrict__ attn_W,
                                  const float* __restrict__ w_ih,
                                  const float* __restrict__ w_hh,
                                  const float* __restrict__ b_ih,
                                  const float* __restrict__ b_hh,
                                  const float* __restrict__ h0,
                                  float* __restrict__ c,
                                  float* __restrict__ pa,
                                  float* __restrict__ gates,
                                  unsigned short* __restrict__ hseqb,
                                  unsigned short* __restrict__ xbf,
                                  const unsigned short* __restrict__ ebf,
                                  unsigned* __restrict__ bar) {
    const int g = blockIdx.x;
    const int tid = threadIdx.x;
    const int n0 = g * 16;
    const int pb = g >> 1;
    const int half = g & 1;

    __shared__ __attribute__((aligned(16))) unsigned short wlds[16 * 1544];  // 49408 B
    __shared__ __attribute__((aligned(16))) float abuf[512];
    __shared__ float scp[4][64];
    __shared__ float sc[64];
    __shared__ float hloc[256];

    // Stage this block's 16 gate-rows of [w_ih | w_hh] as bf16 into LDS.
    for (int idx = tid; idx < 16 * 1024; idx += 256) {
        int row = idx >> 10, k = idx & 1023;
        wlds[row * 1544 + k] = f32_to_bf16_rne(w_ih[(size_t)(n0 + row) * 1024 + k]);
    }
    for (int idx = tid; idx < 16 * 512; idx += 256) {
        int row = idx >> 9, k = idx & 511;
        wlds[row * 1544 + 1024 + k] = f32_to_bf16_rne(w_hh[(size_t)(n0 + row) * 512 + k]);
    }

    // Prologue: xbf h-segment + partial_a from h0.
    {
        float hv = h0[pb * 512 + half * 256 + tid];
        hloc[tid] = hv;
        xbf[pb * 1536 + 1024 + half * 256 + tid] = f32_to_bf16_rne(hv);
    }
    __syncthreads();
    {
        int d0 = tid, d1 = tid + 256;
        float a0 = 0.f, a1 = 0.f;
        const float* wp = attn_W + (size_t)(half * 256) * 512;
#pragma unroll 4
        for (int j = 0; j < 256; j++) {
            float hv = hloc[j];
            a0 += hv * wp[(size_t)j * 512 + d0];
            a1 += hv * wp[(size_t)j * 512 + d1];
        }
        pa[(size_t)g * 512 + d0] = a0;
        pa[(size_t)g * 512 + d1] = a1;
    }

    unsigned target = 128;
    grid_sync_fn(bar, target); target += 128;

    for (int t = 0; t < T; t++) {
        // ---------------- Phase A ----------------
        if (g < 64) {
            int b = g;
            int d0 = tid, d1 = tid + 256;
            abuf[d0] = pa[(size_t)(2 * b) * 512 + d0] + pa[(size_t)(2 * b + 1) * 512 + d0];
            abuf[d1] = pa[(size_t)(2 * b) * 512 + d1] + pa[(size_t)(2 * b + 1) * 512 + d1];
            __syncthreads();
            {
                int s = tid & 63, q = tid >> 6;
                const float4* e4 = (const float4*)(enc_out + ((size_t)b * 64 + s) * 512 + q * 128);
                const float4* a4 = (const float4*)(abuf + q * 128);
                float acc = 0.f;
#pragma unroll 8
                for (int k = 0; k < 32; k++) {
                    float4 e = e4[k];
                    float4 a = a4[k];
                    acc += e.x * a.x + e.y * a.y + e.z * a.z + e.w * a.w;
                }
                scp[q][s] = acc;
            }
            __syncthreads();
            if (tid < 64) {
                float v = scp[0][tid] + scp[1][tid] + scp[2][tid] + scp[3][tid];
                float m = v;
                for (int off = 32; off > 0; off >>= 1) m = fmaxf(m, __shfl_xor(m, off, 64));
                float e = __expf(v - m);
                float ssum = e;
                for (int off = 32; off > 0; off >>= 1) ssum += __shfl_xor(ssum, off, 64);
                sc[tid] = e / ssum;
            }
            __syncthreads();
            {
                float acc0 = 0.f, acc1 = 0.f;
                const float* ep = enc_out + (size_t)b * 64 * 512;
#pragma unroll 4
                for (int s = 0; s < 64; s++) {
                    float a_ = sc[s];
                    acc0 += a_ * ep[(size_t)s * 512 + d0];
                    acc1 += a_ * ep[(size_t)s * 512 + d1];
                }
                xbf[b * 1536 + d0] = f32_to_bf16_rne(acc0);
                xbf[b * 1536 + d1] = f32_to_bf16_rne(acc1);
            }
        } else {
            int b = g - 64;
            const unsigned short* ep = ebf + ((size_t)b * T + t) * 512;
            xbf[b * 1536 + 512 + tid] = ep[tid];
            xbf[b * 1536 + 512 + tid + 256] = ep[tid + 256];
        }
        grid_sync_fn(bar, target); target += 128;

        // ---------------- Phase B: gates MFMA ----------------
        {
            int w = tid >> 6, lane = tid & 63;
            int col = lane & 15, kq = lane >> 4;
            int m0 = w * 16;
            const unsigned short* arow = xbf + (size_t)(m0 + col) * 1536 + kq * 8;
            const unsigned short* brow = wlds + col * 1544 + kq * 8;
            f32x4 acc = {0.f, 0.f, 0.f, 0.f};
#pragma unroll
            for (int ks = 0; ks < 48; ks++) {
                bf16x8 af = *reinterpret_cast<const bf16x8*>(arow + ks * 32);
                bf16x8 bf = *reinterpret_cast<const bf16x8*>(brow + ks * 32);
                acc = __builtin_amdgcn_mfma_f32_16x16x32_bf16(af, bf, acc, 0, 0, 0);
            }
#pragma unroll
            for (int reg = 0; reg < 4; reg++) {
                gates[(size_t)(m0 + kq * 4 + reg) * 2048 + n0 + col] = acc[reg];
            }
        }
        grid_sync_fn(bar, target); target += 128;

        // ---------------- Phase C: LSTM update + next partial_a ----------------
        {
            int u = half * 256 + tid;
            const float* gb = gates + (size_t)pb * 2048;
            float gi = gb[u]        + b_ih[u]        + b_hh[u];
            float gf = gb[512 + u]  + b_ih[512 + u]  + b_hh[512 + u];
            float gg = gb[1024 + u] + b_ih[1024 + u] + b_hh[1024 + u];
            float go = gb[1536 + u] + b_ih[1536 + u] + b_hh[1536 + u];
            float ig = 1.f / (1.f + __expf(-gi));
            float fg = 1.f / (1.f + __expf(-gf));
            float gt = tanhf(gg);
            float og = 1.f / (1.f + __expf(-go));
            float cn = fg * c[pb * 512 + u] + ig * gt;
            float hn = og * tanhf(cn);
            c[pb * 512 + u] = cn;
            unsigned short hb = f32_to_bf16_rne(hn);
            hseqb[((size_t)pb * T + t) * 512 + u] = hb;
            xbf[pb * 1536 + 1024 + u] = hb;
            __syncthreads();
            hloc[tid] = hn;
            __syncthreads();
            int d0 = tid, d1 = tid + 256;
            float a0 = 0.f, a1 = 0.f;
            const float* wp = attn_W + (size_t)(half * 256) * 512;
#pragma unroll 4
            for (int j = 0; j < 256; j++) {
                float hv = hloc[j];
                a0 += hv * wp[(size_t)j * 512 + d0];
                a1 += hv * wp[(size_t)j * 512 + d1];
            }
            pa[(size_t)g * 512 + d0] = a0;
            pa[(size_t)g * 512 + d1] = a1;
        }
        grid_sync_fn(bar, target); target += 128;
    }
}

// ---------------------------------------------------------------------------
// Projection + exp-sum via bf16 MFMA. grid(500), block(256).
// Wave w owns 16 vocab cols; B fragments hoisted to registers (16 x bf16x8);
// 4 independent M-tile accumulation chains per k-step for ILP.
// ---------------------------------------------------------------------------
__global__ void proj_mfma_kernel(const unsigned short* __restrict__ hseqb,
                                 const unsigned short* __restrict__ wbf,
                                 const float* __restrict__ proj_b,
                                 float* __restrict__ partial) {
    int tid = threadIdx.x;
    int w = tid >> 6;
    int lane = tid & 63;
    int col = lane & 15;
    int kq = lane >> 4;
    int n0 = blockIdx.x * 64;
    int n = n0 + w * 16 + col;

    float bias = proj_b[n];
    const unsigned short* wrow = wbf + (size_t)n * 512 + kq * 8;
    bf16x8 Bf[16];
#pragma unroll
    for (int ks = 0; ks < 16; ks++)
        Bf[ks] = *reinterpret_cast<const bf16x8*>(wrow + ks * 32);

    __shared__ float sums[4][64];

    for (int mg = 0; mg < 21; mg++) {
        int m0 = mg * 64;
        const unsigned short* abase = hseqb + (size_t)(m0 + col) * 512 + kq * 8;
        f32x4 acc[4] = {{0.f, 0.f, 0.f, 0.f}, {0.f, 0.f, 0.f, 0.f},
                        {0.f, 0.f, 0.f, 0.f}, {0.f, 0.f, 0.f, 0.f}};
#pragma unroll
        for (int ks = 0; ks < 16; ks++) {
#pragma unroll
            for (int ti = 0; ti < 4; ti++) {
                bf16x8 af = *reinterpret_cast<const bf16x8*>(abase + (size_t)ti * 16 * 512 + ks * 32);
                acc[ti] = __builtin_amdgcn_mfma_f32_16x16x32_bf16(af, Bf[ks], acc[ti], 0, 0, 0);
            }
        }
#pragma unroll
        for (int ti = 0; ti < 4; ti++) {
#pragma unroll
            for (int reg = 0; reg < 4; reg++) {
                float e = __expf(acc[ti][reg] + bias);
                e += __shfl_xor(e, 1, 64);
                e += __shfl_xor(e, 2, 64);
                e += __shfl_xor(e, 4, 64);
                e += __shfl_xor(e, 8, 64);
                if (col == 0) sums[w][ti * 16 + kq * 4 + reg] = e;
            }
        }
        __syncthreads();
        if (tid < 64) {
            partial[(size_t)blockIdx.x * 1344 + m0 + tid] =
                sums[0][tid] + sums[1][tid] + sums[2][tid] + sums[3][tid];
        }
        __syncthreads();
    }
}

// ---------------------------------------------------------------------------
// Reduce partial[500][1344] -> sumexp[1344]. grid(6), block(256)
// ---------------------------------------------------------------------------
__global__ void sumexp_reduce_kernel(const float* __restrict__ partial,
                                     float* __restrict__ sumexp) {
    int m = blockIdx.x * 256 + threadIdx.x;
    if (m >= 1344) return;
    float s = 0.f;
    for (int nb = 0; nb < 500; nb++) s += partial[(size_t)nb * 1344 + m];
    sumexp[m] = s;
}

// ---------------------------------------------------------------------------
// Final loss. grid(64), block(64). h from bf16 hseqb, w fp32.
// ---------------------------------------------------------------------------
__global__ void loss_kernel(const unsigned short* __restrict__ hseqb,
                            const float* __restrict__ proj_w,
                            const float* __restrict__ proj_b,
                            const float* __restrict__ sumexp,
                            const int* __restrict__ seq_label,
                            float* __restrict__ out) {
    int b = blockIdx.x;
    int lane = threadIdx.x;
    float num = 0.f, den = 0.f;
    for (int t = 0; t < T; t++) {
        int label = seq_label[b * T + t];
        const unsigned short* hp = hseqb + ((size_t)b * T + t) * 512;
        const float* wp = proj_w + (size_t)label * 512;
        float acc = 0.f;
#pragma unroll
        for (int i = 0; i < 8; i++)
            acc += bf16_to_f32(hp[lane + 64 * i]) * wp[lane + 64 * i];
        for (int off = 32; off > 0; off >>= 1) acc += __shfl_xor(acc, off, 64);
        if (lane == 0) {
            float nll = logf(sumexp[b * T + t]) - (acc + proj_b[label]);
            float mask = (label > 0) ? 1.f : 0.f;
            num += mask * nll;
            den += mask;
        }
    }
    if (lane == 0) {
        atomicAdd(out, (num / (den + 1e-6f)) * (1.f / 64.f));
    }
}

// ---------------------------------------------------------------------------
extern "C" void kernel_launch(void* const* d_in, const int* in_sizes, int n_in,
                              void* d_out, int out_size, void* d_ws, size_t ws_size,
                              hipStream_t stream) {
    const float* enc_h     = (const float*)d_in[0];
    const float* enc_out   = (const float*)d_in[1];
    const int*   seq_label = (const int*)d_in[3];
    const int*   dec_in    = (const int*)d_in[4];
    const float* style     = (const float*)d_in[5];
    const float* W_e2d_w   = (const float*)d_in[6];
    const float* W_e2d_b   = (const float*)d_in[7];
    const float* attn_W    = (const float*)d_in[8];
    const float* emb_table = (const float*)d_in[9];
    const float* w_ih      = (const float*)d_in[10];
    const float* w_hh      = (const float*)d_in[11];
    const float* b_ih      = (const float*)d_in[12];
    const float* b_hh      = (const float*)d_in[13];
    const float* proj_w    = (const float*)d_in[14];
    const float* proj_b    = (const float*)d_in[15];
    float* out = (float*)d_out;

    // workspace layout
    float* h       = (float*)d_ws;           // 32768
    float* c       = h + 32768;              // 32768
    float* pa      = c + 32768;              // 128*512 = 65536
    float* gates   = pa + 65536;             // 64*2048 = 131072
    float* sumexp  = gates + 131072;         // 1344
    float* partial = sumexp + 1344;          // 500*1344 = 672000
    unsigned* bar  = (unsigned*)(partial + 672000);               // 64
    unsigned short* hseqb = (unsigned short*)(bar + 64);          // 688128
    unsigned short* wbf   = hseqb + 688128;  // 16384000
    unsigned short* xbf   = wbf + 16384000;  // 64*1536 = 98304
    unsigned short* ebf   = xbf + 98304;     // 688128

    hipMemsetAsync(out, 0, sizeof(float), stream);
    hipMemsetAsync(bar, 0, sizeof(unsigned), stream);

    h0_kernel<<<64, 256, 0, stream>>>(enc_h, style, W_e2d_w, W_e2d_b, h, c);
    ebf_kernel<<<64 * T, 256, 0, stream>>>(emb_table, dec_in, ebf);
    wconv_kernel<<<8000, 256, 0, stream>>>(proj_w, wbf);

    {
        void* args[] = {(void*)&enc_out, (void*)&attn_W, (void*)&w_ih, (void*)&w_hh,
                        (void*)&b_ih, (void*)&b_hh, (void*)&h, (void*)&c, (void*)&pa,
                        (void*)&gates, (void*)&hseqb, (void*)&xbf, (void*)&ebf,
                        (void*)&bar};
        hipLaunchCooperativeKernel((const void*)fused_scan_kernel, dim3(128),
                                   dim3(256), args, 0, stream);
    }

    proj_mfma_kernel<<<500, 256, 0, stream>>>(hseqb, wbf, proj_b, partial);
    sumexp_reduce_kernel<<<6, 256, 0, stream>>>(partial, sumexp);
    loss_kernel<<<64, 64, 0, stream>>>(hseqb, proj_w, proj_b, sumexp, seq_label, out);
}

// Round 4
// 904.263 us; speedup vs baseline: 3.1649x; 3.1649x over previous
//
#include <hip/hip_runtime.h>
#include <hip/hip_bf16.h>
#include <math.h>

#define B 64
#define S 64
#define T 21
#define ENC_D 512
#define HID 512
#define VOCAB 32000

typedef __bf16 bf16x8 __attribute__((ext_vector_type(8)));
typedef float f32x4 __attribute__((ext_vector_type(4)));

union BF8 { unsigned short u[8]; bf16x8 v; uint4 q; };

__device__ __forceinline__ unsigned short f32_to_bf16_rne(float x) {
    union { float f; unsigned int u; } v;
    v.f = x;
    unsigned int u = v.u;
    unsigned int r = (u + 0x7FFFu + ((u >> 16) & 1u)) >> 16;
    return (unsigned short)r;
}

__device__ __forceinline__ float bf16_to_f32(unsigned short x) {
    union { unsigned int u; float f; } v;
    v.u = ((unsigned int)x) << 16;
    return v.f;
}

// ---------------------------------------------------------------------------
// h0 = concat(encode_hidden, style_emb[:,3,:]) @ W_e2d_w.T + b  -> hbuf0 bf16
// c[u][b] = 0.   grid(64), block(256)
// ---------------------------------------------------------------------------
__global__ __launch_bounds__(256) void h0_kernel(
        const float* __restrict__ enc_h, const float* __restrict__ style,
        const float* __restrict__ W, const float* __restrict__ bias,
        unsigned short* __restrict__ hbf0, float* __restrict__ c) {
    int b = blockIdx.x;
    int tid = threadIdx.x;
    __shared__ __attribute__((aligned(16))) float in[640];
    for (int i = tid; i < 512; i += 256) in[i] = enc_h[b * 512 + i];
    if (tid < 128) in[512 + tid] = style[b * 512 + 384 + tid];
    __syncthreads();
    for (int j = tid; j < 512; j += 256) {
        const float4* w4 = (const float4*)(W + (size_t)j * 640);
        float acc = 0.f;
#pragma unroll 4
        for (int k4 = 0; k4 < 160; k4++) {
            float4 w = w4[k4];
            float4 iv = *(const float4*)(in + k4 * 4);
            acc += w.x * iv.x + w.y * iv.y + w.z * iv.z + w.w * iv.w;
        }
        hbf0[b * 512 + j] = f32_to_bf16_rne(acc + bias[j]);
        c[j * 64 + b] = 0.f;
    }
}

// ---------------------------------------------------------------------------
// enc_out fp32 -> bf16 (2M elems). grid(1024), block(256), 8/thread
// ---------------------------------------------------------------------------
__global__ __launch_bounds__(256) void encconv_kernel(
        const float* __restrict__ src, unsigned short* __restrict__ dst) {
    size_t i = ((size_t)blockIdx.x * 256 + threadIdx.x) * 8;
    float4 a = *(const float4*)(src + i);
    float4 b = *(const float4*)(src + i + 4);
    BF8 p;
    p.u[0] = f32_to_bf16_rne(a.x); p.u[1] = f32_to_bf16_rne(a.y);
    p.u[2] = f32_to_bf16_rne(a.z); p.u[3] = f32_to_bf16_rne(a.w);
    p.u[4] = f32_to_bf16_rne(b.x); p.u[5] = f32_to_bf16_rne(b.y);
    p.u[6] = f32_to_bf16_rne(b.z); p.u[7] = f32_to_bf16_rne(b.w);
    *(uint4*)(dst + i) = p.q;
}

// ---------------------------------------------------------------------------
// wcbf[n][0:1024] = w_ih[n][:], wcbf[n][1024:1536] = w_hh[n][:]  (bf16)
// grid(2048), block(256)
// ---------------------------------------------------------------------------
__global__ __launch_bounds__(256) void wcconv_kernel(
        const float* __restrict__ w_ih, const float* __restrict__ w_hh,
        unsigned short* __restrict__ wcbf) {
    int n = blockIdx.x;
    int tid = threadIdx.x;
    for (int k = tid; k < 1536; k += 256) {
        float v = (k < 1024) ? w_ih[(size_t)n * 1024 + k]
                             : w_hh[(size_t)n * 512 + (k - 1024)];
        wcbf[(size_t)n * 1536 + k] = f32_to_bf16_rne(v);
    }
}

// ---------------------------------------------------------------------------
// M[bs][j] = sum_d encbf[bs][d] * attn_W[j][d]   (bf16 out)
// grid(64, 8), block(256): 64-bs x 64-j tile; wave w: rows w*16.
// B fragments converted fp32->bf16 inline.
// ---------------------------------------------------------------------------
__global__ __launch_bounds__(256) void mgemm_kernel(
        const unsigned short* __restrict__ encbf,
        const float* __restrict__ attn_W,
        unsigned short* __restrict__ M_bf) {
    int tid = threadIdx.x;
    int w = tid >> 6, lane = tid & 63;
    int col = lane & 15, kq = lane >> 4;
    int m0 = blockIdx.x * 64 + w * 16;

    bf16x8 af[16];
    const unsigned short* arow = encbf + (size_t)(m0 + col) * 512 + kq * 8;
#pragma unroll
    for (int ks = 0; ks < 16; ks++)
        af[ks] = *reinterpret_cast<const bf16x8*>(arow + ks * 32);

#pragma unroll
    for (int nt = 0; nt < 4; nt++) {
        int j0 = blockIdx.y * 64 + nt * 16;
        const float* brow = attn_W + (size_t)(j0 + col) * 512 + kq * 8;
        f32x4 acc = {0.f, 0.f, 0.f, 0.f};
#pragma unroll
        for (int ks = 0; ks < 16; ks++) {
            float4 f0 = *(const float4*)(brow + ks * 32);
            float4 f1 = *(const float4*)(brow + ks * 32 + 4);
            BF8 p;
            p.u[0] = f32_to_bf16_rne(f0.x); p.u[1] = f32_to_bf16_rne(f0.y);
            p.u[2] = f32_to_bf16_rne(f0.z); p.u[3] = f32_to_bf16_rne(f0.w);
            p.u[4] = f32_to_bf16_rne(f1.x); p.u[5] = f32_to_bf16_rne(f1.y);
            p.u[6] = f32_to_bf16_rne(f1.z); p.u[7] = f32_to_bf16_rne(f1.w);
            acc = __builtin_amdgcn_mfma_f32_16x16x32_bf16(af[ks], p.v, acc, 0, 0, 0);
        }
#pragma unroll
        for (int reg = 0; reg < 4; reg++) {
            int m = m0 + kq * 4 + reg;
            M_bf[(size_t)m * 512 + j0 + col] = f32_to_bf16_rne(acc[reg]);
        }
    }
}

// ---------------------------------------------------------------------------
// K1 per step: scores[b][s] = M[b][s]·h[b]; softmax; ctx = attn @ enc.
// grid(64)=b, block(256). h kept in registers (lane owns j-slice of 8).
// ---------------------------------------------------------------------------
__global__ __launch_bounds__(256) void attn_step_kernel(
        const unsigned short* __restrict__ hbf_in,
        const unsigned short* __restrict__ M_bf,
        const unsigned short* __restrict__ encbf,
        unsigned short* __restrict__ xbf) {
    int b = blockIdx.x;
    int tid = threadIdx.x;
    int lane = tid & 63, sg = tid >> 6;

    __shared__ float scp[64];
    __shared__ float sc[64];

    // lane's h slice: j = lane*8 .. +8
    float hreg[8];
    {
        BF8 hp;
        hp.v = *reinterpret_cast<const bf16x8*>(hbf_in + b * 512 + lane * 8);
#pragma unroll
        for (int i = 0; i < 8; i++) hreg[i] = bf16_to_f32(hp.u[i]);
    }

    // scores: wave sg handles s = sg*16 .. +16
    for (int si = 0; si < 16; si++) {
        int s = sg * 16 + si;
        BF8 mp;
        mp.v = *reinterpret_cast<const bf16x8*>(M_bf + ((size_t)(b * 64 + s)) * 512 + lane * 8);
        float acc = 0.f;
#pragma unroll
        for (int i = 0; i < 8; i++) acc += bf16_to_f32(mp.u[i]) * hreg[i];
        for (int off = 32; off > 0; off >>= 1) acc += __shfl_xor(acc, off, 64);
        if (lane == 0) scp[s] = acc;
    }
    __syncthreads();

    if (tid < 64) {
        float v = scp[tid];
        float m = v;
        for (int off = 32; off > 0; off >>= 1) m = fmaxf(m, __shfl_xor(m, off, 64));
        float e = __expf(v - m);
        float ssum = e;
        for (int off = 32; off > 0; off >>= 1) ssum += __shfl_xor(ssum, off, 64);
        sc[tid] = e / ssum;
    }
    __syncthreads();

    // ctx[d] = sum_s sc[s] * encbf[b][s][d]
    {
        int d0 = tid, d1 = tid + 256;
        float a0 = 0.f, a1 = 0.f;
        const unsigned short* ep = encbf + (size_t)b * 64 * 512;
#pragma unroll 4
        for (int s = 0; s < 64; s++) {
            float a = sc[s];
            a0 += a * bf16_to_f32(ep[(size_t)s * 512 + d0]);
            a1 += a * bf16_to_f32(ep[(size_t)s * 512 + d1]);
        }
        xbf[b * 512 + d0] = f32_to_bf16_rne(a0);
        xbf[b * 512 + d1] = f32_to_bf16_rne(a1);
    }
}

// ---------------------------------------------------------------------------
// K2 per step: gates for u-tile of 4 (16 gate rows) x all 64 b via MFMA;
// then LSTM update. grid(128), block(256).
// A = [ctx | emb | h] (K=1536): ctx from xbf, emb gathered+converted inline,
// h from hbf_in.  B = wcbf rows staged in LDS (stride 1544 us).
// ---------------------------------------------------------------------------
__global__ __launch_bounds__(256) void gates_step_kernel(
        const unsigned short* __restrict__ xbf,
        const unsigned short* __restrict__ hbf_in,
        unsigned short* __restrict__ hbf_out,
        const float* __restrict__ emb_table,
        const int* __restrict__ dec_in,
        const unsigned short* __restrict__ wcbf,
        const float* __restrict__ b_ih, const float* __restrict__ b_hh,
        float* __restrict__ c, unsigned short* __restrict__ hseqb, int t) {
    int tid = threadIdx.x;
    int u0 = blockIdx.x * 4;
    int w = tid >> 6, lane = tid & 63;
    int col = lane & 15, kq = lane >> 4;

    __shared__ __attribute__((aligned(16))) unsigned short blds[16 * 1544];
    __shared__ float glds[64 * 17];

    // Stage B: 16 gate rows {u0..u0+3} x {i,f,g,o quarters}
#pragma unroll
    for (int i = 0; i < 12; i++) {
        int idx = i * 256 + tid;          // 0..3071, each = 8 ushorts
        int r = idx / 192, c8 = (idx % 192) * 8;
        int gr = (r >> 2) * 512 + u0 + (r & 3);
        *(uint4*)(blds + r * 1544 + c8) =
            *(const uint4*)(wcbf + (size_t)gr * 1536 + c8);
    }
    __syncthreads();

    // MFMA: wave w covers b = w*16 + col (A rows), n = col (B rows)
    int bA = w * 16 + col;
    int tok = dec_in[bA * T + t];
    const unsigned short* ctxrow = xbf + bA * 512 + kq * 8;
    const unsigned short* hrow = hbf_in + bA * 512 + kq * 8;
    const float* erow = emb_table + (size_t)tok * 512 + kq * 8;
    const unsigned short* brow = blds + col * 1544 + kq * 8;

    f32x4 acc = {0.f, 0.f, 0.f, 0.f};
#pragma unroll
    for (int ks = 0; ks < 16; ks++) {
        bf16x8 af = *reinterpret_cast<const bf16x8*>(ctxrow + ks * 32);
        bf16x8 bf = *reinterpret_cast<const bf16x8*>(brow + ks * 32);
        acc = __builtin_amdgcn_mfma_f32_16x16x32_bf16(af, bf, acc, 0, 0, 0);
    }
#pragma unroll
    for (int ks = 0; ks < 16; ks++) {
        float4 f0 = *(const float4*)(erow + ks * 32);
        float4 f1 = *(const float4*)(erow + ks * 32 + 4);
        BF8 p;
        p.u[0] = f32_to_bf16_rne(f0.x); p.u[1] = f32_to_bf16_rne(f0.y);
        p.u[2] = f32_to_bf16_rne(f0.z); p.u[3] = f32_to_bf16_rne(f0.w);
        p.u[4] = f32_to_bf16_rne(f1.x); p.u[5] = f32_to_bf16_rne(f1.y);
        p.u[6] = f32_to_bf16_rne(f1.z); p.u[7] = f32_to_bf16_rne(f1.w);
        bf16x8 bf = *reinterpret_cast<const bf16x8*>(brow + (16 + ks) * 32);
        acc = __builtin_amdgcn_mfma_f32_16x16x32_bf16(p.v, bf, acc, 0, 0, 0);
    }
#pragma unroll
    for (int ks = 0; ks < 16; ks++) {
        bf16x8 af = *reinterpret_cast<const bf16x8*>(hrow + ks * 32);
        bf16x8 bf = *reinterpret_cast<const bf16x8*>(brow + (32 + ks) * 32);
        acc = __builtin_amdgcn_mfma_f32_16x16x32_bf16(af, bf, acc, 0, 0, 0);
    }

    // scatter C to LDS: glds[b][n_local], b = w*16 + kq*4 + reg, n_local = col
#pragma unroll
    for (int reg = 0; reg < 4; reg++) {
        glds[(w * 16 + kq * 4 + reg) * 17 + col] = acc[reg];
    }
    __syncthreads();

    // LSTM update: thread = (u_l = tid>>6, b = tid&63)
    {
        int b = tid & 63, u_l = tid >> 6;
        int u = u0 + u_l;
        float gi = glds[b * 17 + u_l]      + b_ih[u]        + b_hh[u];
        float gf = glds[b * 17 + 4 + u_l]  + b_ih[512 + u]  + b_hh[512 + u];
        float gg = glds[b * 17 + 8 + u_l]  + b_ih[1024 + u] + b_hh[1024 + u];
        float go = glds[b * 17 + 12 + u_l] + b_ih[1536 + u] + b_hh[1536 + u];
        float ig = 1.f / (1.f + __expf(-gi));
        float fg = 1.f / (1.f + __expf(-gf));
        float gt = tanhf(gg);
        float og = 1.f / (1.f + __expf(-go));
        float cn = fg * c[u * 64 + b] + ig * gt;
        float hn = og * tanhf(cn);
        c[u * 64 + b] = cn;
        unsigned short hb = f32_to_bf16_rne(hn);
        hbf_out[b * 512 + u] = hb;
        hseqb[((size_t)b * T + t) * 512 + u] = hb;
    }
}

// ---------------------------------------------------------------------------
// Projection + exp-sum. grid(500), block(256). B frags (proj_w) converted
// fp32->bf16 inline, hoisted; A tiles staged in LDS (stride 520 us).
// ---------------------------------------------------------------------------
__global__ __launch_bounds__(256) void proj_mfma_kernel(
        const unsigned short* __restrict__ hseqb,
        const float* __restrict__ proj_w,
        const float* __restrict__ proj_b,
        float* __restrict__ partial) {
    int tid = threadIdx.x;
    int w = tid >> 6, lane = tid & 63;
    int col = lane & 15, kq = lane >> 4;
    int n = blockIdx.x * 64 + w * 16 + col;

    float bias = proj_b[n];
    bf16x8 Bf[16];
    {
        const float* wrow = proj_w + (size_t)n * 512 + kq * 8;
#pragma unroll
        for (int ks = 0; ks < 16; ks++) {
            float4 f0 = *(const float4*)(wrow + ks * 32);
            float4 f1 = *(const float4*)(wrow + ks * 32 + 4);
            BF8 p;
            p.u[0] = f32_to_bf16_rne(f0.x); p.u[1] = f32_to_bf16_rne(f0.y);
            p.u[2] = f32_to_bf16_rne(f0.z); p.u[3] = f32_to_bf16_rne(f0.w);
            p.u[4] = f32_to_bf16_rne(f1.x); p.u[5] = f32_to_bf16_rne(f1.y);
            p.u[6] = f32_to_bf16_rne(f1.z); p.u[7] = f32_to_bf16_rne(f1.w);
            Bf[ks] = p.v;
        }
    }

    __shared__ __attribute__((aligned(16))) unsigned short alds[64 * 520];
    __shared__ float sums[4][64];

    for (int mg = 0; mg < 21; mg++) {
        int m0 = mg * 64;
        __syncthreads();
#pragma unroll
        for (int i = 0; i < 16; i++) {
            int idx = i * 256 + tid;      // 0..4095, each = 8 ushorts
            int row = idx >> 6, c8 = (idx & 63) * 8;
            *(uint4*)(alds + row * 520 + c8) =
                *(const uint4*)(hseqb + (size_t)(m0 + row) * 512 + c8);
        }
        __syncthreads();

        f32x4 acc[4] = {{0.f, 0.f, 0.f, 0.f}, {0.f, 0.f, 0.f, 0.f},
                        {0.f, 0.f, 0.f, 0.f}, {0.f, 0.f, 0.f, 0.f}};
#pragma unroll
        for (int ks = 0; ks < 16; ks++) {
#pragma unroll
            for (int ti = 0; ti < 4; ti++) {
                bf16x8 af = *reinterpret_cast<const bf16x8*>(
                    alds + (ti * 16 + col) * 520 + kq * 8 + ks * 32);
                acc[ti] = __builtin_amdgcn_mfma_f32_16x16x32_bf16(af, Bf[ks], acc[ti], 0, 0, 0);
            }
        }
#pragma unroll
        for (int ti = 0; ti < 4; ti++) {
#pragma unroll
            for (int reg = 0; reg < 4; reg++) {
                float e = __expf(acc[ti][reg] + bias);
                e += __shfl_xor(e, 1, 64);
                e += __shfl_xor(e, 2, 64);
                e += __shfl_xor(e, 4, 64);
                e += __shfl_xor(e, 8, 64);
                if (col == 0) sums[w][ti * 16 + kq * 4 + reg] = e;
            }
        }
        __syncthreads();
        if (tid < 64) {
            partial[(size_t)blockIdx.x * 1344 + m0 + tid] =
                sums[0][tid] + sums[1][tid] + sums[2][tid] + sums[3][tid];
        }
    }
}

// ---------------------------------------------------------------------------
__global__ __launch_bounds__(256) void sumexp_reduce_kernel(
        const float* __restrict__ partial, float* __restrict__ sumexp) {
    int m = blockIdx.x * 256 + threadIdx.x;
    if (m >= 1344) return;
    float s = 0.f;
    for (int nb = 0; nb < 500; nb++) s += partial[(size_t)nb * 1344 + m];
    sumexp[m] = s;
}

// ---------------------------------------------------------------------------
__global__ __launch_bounds__(64) void loss_kernel(
        const unsigned short* __restrict__ hseqb,
        const float* __restrict__ proj_w, const float* __restrict__ proj_b,
        const float* __restrict__ sumexp, const int* __restrict__ seq_label,
        float* __restrict__ out) {
    int b = blockIdx.x;
    int lane = threadIdx.x;
    float num = 0.f, den = 0.f;
    for (int t = 0; t < T; t++) {
        int label = seq_label[b * T + t];
        const unsigned short* hp = hseqb + ((size_t)b * T + t) * 512;
        const float* wp = proj_w + (size_t)label * 512;
        float acc = 0.f;
#pragma unroll
        for (int i = 0; i < 8; i++)
            acc += bf16_to_f32(hp[lane + 64 * i]) * wp[lane + 64 * i];
        for (int off = 32; off > 0; off >>= 1) acc += __shfl_xor(acc, off, 64);
        if (lane == 0) {
            float nll = logf(sumexp[b * T + t]) - (acc + proj_b[label]);
            float mask = (label > 0) ? 1.f : 0.f;
            num += mask * nll;
            den += mask;
        }
    }
    if (lane == 0) atomicAdd(out, (num / (den + 1e-6f)) * (1.f / 64.f));
}

// ---------------------------------------------------------------------------
extern "C" void kernel_launch(void* const* d_in, const int* in_sizes, int n_in,
                              void* d_out, int out_size, void* d_ws, size_t ws_size,
                              hipStream_t stream) {
    const float* enc_h     = (const float*)d_in[0];
    const float* enc_out   = (const float*)d_in[1];
    const int*   seq_label = (const int*)d_in[3];
    const int*   dec_in    = (const int*)d_in[4];
    const float* style     = (const float*)d_in[5];
    const float* W_e2d_w   = (const float*)d_in[6];
    const float* W_e2d_b   = (const float*)d_in[7];
    const float* attn_W    = (const float*)d_in[8];
    const float* emb_table = (const float*)d_in[9];
    const float* w_ih      = (const float*)d_in[10];
    const float* w_hh      = (const float*)d_in[11];
    const float* b_ih      = (const float*)d_in[12];
    const float* b_hh      = (const float*)d_in[13];
    const float* proj_w    = (const float*)d_in[14];
    const float* proj_b    = (const float*)d_in[15];
    float* out = (float*)d_out;

    // workspace layout (all offsets 16B-aligned)
    char* p = (char*)d_ws;
    float* c        = (float*)p;            p += 512 * 64 * 4;        // 131072
    float* partial  = (float*)p;            p += 500 * 1344 * 4;      // 2688000
    float* sumexp   = (float*)p;            p += 1344 * 4 + 64;
    unsigned short* M_bf  = (unsigned short*)p; p += 4096 * 512 * 2;  // 4 MB
    unsigned short* encbf = (unsigned short*)p; p += 4096 * 512 * 2;  // 4 MB
    unsigned short* wcbf  = (unsigned short*)p; p += 2048 * 1536 * 2; // 6 MB
    unsigned short* hseqb = (unsigned short*)p; p += 1344 * 512 * 2;  // 1.4 MB
    unsigned short* hbuf0 = (unsigned short*)p; p += 64 * 512 * 2;
    unsigned short* hbuf1 = (unsigned short*)p; p += 64 * 512 * 2;
    unsigned short* xbf   = (unsigned short*)p; p += 64 * 512 * 2;
    unsigned short* hb[2] = {hbuf0, hbuf1};

    hipMemsetAsync(out, 0, sizeof(float), stream);

    h0_kernel<<<64, 256, 0, stream>>>(enc_h, style, W_e2d_w, W_e2d_b, hbuf0, c);
    encconv_kernel<<<1024, 256, 0, stream>>>(enc_out, encbf);
    wcconv_kernel<<<2048, 256, 0, stream>>>(w_ih, w_hh, wcbf);
    mgemm_kernel<<<dim3(64, 8), 256, 0, stream>>>(encbf, attn_W, M_bf);

    for (int t = 0; t < T; t++) {
        attn_step_kernel<<<64, 256, 0, stream>>>(hb[t & 1], M_bf, encbf, xbf);
        gates_step_kernel<<<128, 256, 0, stream>>>(xbf, hb[t & 1], hb[(t + 1) & 1],
                                                   emb_table, dec_in, wcbf,
                                                   b_ih, b_hh, c, hseqb, t);
    }

    proj_mfma_kernel<<<500, 256, 0, stream>>>(hseqb, proj_w, proj_b, partial);
    sumexp_reduce_kernel<<<6, 256, 0, stream>>>(partial, sumexp);
    loss_kernel<<<64, 64, 0, stream>>>(hseqb, proj_w, proj_b, sumexp, seq_label, out);
}